// Round 2
// baseline (122.553 us; speedup 1.0000x reference)
//
#include <hip/hip_runtime.h>
#include <stdint.h>

#define BATCH 8
#define LTOK 1024
#define DMODEL 512
#define NHEAD 8
#define DHEAD 64

typedef unsigned short u16;
typedef u16 u16x8 __attribute__((ext_vector_type(8)));
typedef short bf16x8 __attribute__((ext_vector_type(8)));
typedef float f32x4 __attribute__((ext_vector_type(4)));

#define MFMA16(a,b,c) __builtin_amdgcn_mfma_f32_16x16x32_bf16((a),(b),(c),0,0,0)

__device__ __forceinline__ float bf2f(u16 x){
  union{unsigned u; float f;} v; v.u = ((unsigned)x)<<16; return v.f;
}
__device__ __forceinline__ u16 f2bf(float f){
  union{float f; unsigned u;} v; v.f = f;
  unsigned r = v.u + 0x7fffu + ((v.u>>16)&1u);
  return (u16)(r>>16);
}

// ---------------- fp32 -> bf16 elementwise convert ------------------------------
__global__ __launch_bounds__(256) void convert_k(const float* __restrict__ src,
                                                 u16* __restrict__ dst, int n){
  const int i = (blockIdx.x*256 + threadIdx.x)*8;
  if (i >= n) return;
  u16x8 v;
  #pragma unroll
  for (int j=0;j<8;j++) v[j] = f2bf(src[i+j]);
  *(u16x8*)(dst + i) = v;
}

// ---------------- 64x64 tiled transpose fp32->bf16: dst[c][r] = src[r][c] -------
__global__ __launch_bounds__(256) void transpose_f2b(const float* __restrict__ src,
                                                     u16* __restrict__ dst,
                                                     int R, int C){
  __shared__ __align__(16) u16 t[64][72];
  const int b  = blockIdx.z;
  const int r0 = blockIdx.x*64, c0 = blockIdx.y*64;
  const float* s = src + (size_t)b*R*C;
  u16* d         = dst + (size_t)b*R*C;
  const int tid = threadIdx.x;
  const int row = tid>>3, ch = (tid&7)*8;
  #pragma unroll
  for (int rr=0; rr<64; rr+=32){
    const float* p = s + (size_t)(r0+row+rr)*C + c0 + ch;
    u16x8 v;
    #pragma unroll
    for (int j=0;j<8;j++) v[j] = f2bf(p[j]);
    *(u16x8*)&t[row+rr][ch] = v;
  }
  __syncthreads();
  #pragma unroll
  for (int rr=0; rr<64; rr+=32){
    const int dr = row+rr;
    u16x8 v;
    #pragma unroll
    for (int j=0;j<8;j++) v[j] = t[ch+j][dr];
    *(u16x8*)(d + (size_t)(c0+dr)*R + r0 + ch) = v;
  }
}

// ---------------- 64x64 tiled transpose bf16->bf16 ------------------------------
__global__ __launch_bounds__(256) void transpose_b2b(const u16* __restrict__ src,
                                                     u16* __restrict__ dst,
                                                     int R, int C){
  __shared__ __align__(16) u16 t[64][72];
  const int b  = blockIdx.z;
  const int r0 = blockIdx.x*64, c0 = blockIdx.y*64;
  const u16* s = src + (size_t)b*R*C;
  u16* d       = dst + (size_t)b*R*C;
  const int tid = threadIdx.x;
  const int row = tid>>3, ch = (tid&7)*8;
  #pragma unroll
  for (int rr=0; rr<64; rr+=32){
    u16x8 v = *(const u16x8*)(s + (size_t)(r0+row+rr)*C + c0 + ch);
    *(u16x8*)&t[row+rr][ch] = v;
  }
  __syncthreads();
  #pragma unroll
  for (int rr=0; rr<64; rr+=32){
    const int dr = row+rr;
    u16x8 v;
    #pragma unroll
    for (int j=0;j<8;j++) v[j] = t[ch+j][dr];
    *(u16x8*)(d + (size_t)(c0+dr)*R + r0 + ch) = v;
  }
}

// ---------------- QKV projection: qh[b,h][l][d] = x_rm[l][:] . w[oc][:] ---------
__global__ __launch_bounds__(256) void qkv_gemm(const u16* __restrict__ A,
                                                const u16* __restrict__ W,
                                                u16* __restrict__ qh){
  __shared__ __align__(16) u16 sA[64*64];
  __shared__ __align__(16) u16 sB[64*64];
  const int m0 = blockIdx.x*64, n0 = blockIdx.y*64;
  const int tid = threadIdx.x, w = tid>>6, lane = tid&63;
  const int wr = w>>1, wc = w&1;
  const int lr = lane&15, lg = lane>>4;
  f32x4 acc[2][2] = {};
  for (int kt=0; kt<8; ++kt){
    __syncthreads();
    #pragma unroll
    for (int s2=0; s2<2; ++s2){
      const int slot = tid + s2*256;
      const int row = slot>>3, ch=(slot&7)*8;
      const int k = kt*64 + ch;
      u16x8 va = *(const u16x8*)(A + (size_t)(m0+row)*DMODEL + k);
      u16x8 vb = *(const u16x8*)(W + (size_t)(n0+row)*DMODEL + k);
      const int idx = (row*64 + ch) ^ ((row&7)<<3);
      *(u16x8*)(sA+idx) = va;
      *(u16x8*)(sB+idx) = vb;
    }
    __syncthreads();
    #pragma unroll
    for (int ks=0; ks<2; ++ks){
      bf16x8 af[2], bfr[2];
      #pragma unroll
      for (int mi=0; mi<2; ++mi){
        const int r = wr*32 + mi*16 + lr;
        const int idx = (r*64 + ks*32 + lg*8) ^ ((r&7)<<3);
        af[mi] = *(const bf16x8*)(sA+idx);
      }
      #pragma unroll
      for (int nj=0; nj<2; ++nj){
        const int r = wc*32 + nj*16 + lr;
        const int idx = (r*64 + ks*32 + lg*8) ^ ((r&7)<<3);
        bfr[nj] = *(const bf16x8*)(sB+idx);
      }
      #pragma unroll
      for (int mi=0; mi<2; ++mi)
        #pragma unroll
        for (int nj=0; nj<2; ++nj)
          acc[mi][nj] = MFMA16(af[mi], bfr[nj], acc[mi][nj]);
    }
  }
  #pragma unroll
  for (int mi=0; mi<2; ++mi)
    #pragma unroll
    for (int nj=0; nj<2; ++nj)
      #pragma unroll
      for (int r=0; r<4; ++r){
        const int m = m0 + wr*32 + mi*16 + lg*4 + r;
        const int n = n0 + wc*32 + nj*16 + lr;
        const int b = m>>10, l = m&1023, h = n>>6, d = n&63;
        qh[((size_t)(b*NHEAD+h)*LTOK + l)*DHEAD + d] = f2bf(acc[mi][nj][r]);
      }
}

// ---------------- attention: flash-style per (qtile, h, b) ----------------------
__global__ __launch_bounds__(256) void attn_k(const u16* __restrict__ qh,
                                              const u16* __restrict__ qhT,
                                              u16* __restrict__ ao){
  __shared__ __align__(16) u16 sK[64*64];
  __shared__ __align__(16) u16 sV[64*64];
  __shared__ __align__(16) u16 sP[64*64];
  const int qt = blockIdx.x, h = blockIdx.y, b = blockIdx.z;
  const int bh = b*NHEAD + h;
  const u16* Qb = qh  + (size_t)bh*LTOK*DHEAD;
  const u16* Tb = qhT + (size_t)bh*DHEAD*LTOK;
  const int tid = threadIdx.x, w = tid>>6, lane = tid&63;
  const int i0 = qt*64 + w*16;
  const int lr = lane&15, lg = lane>>4;

  bf16x8 aq[2];
  #pragma unroll
  for (int ks=0; ks<2; ++ks){
    u16x8 v = *(const u16x8*)(Qb + (size_t)(i0+lr)*DHEAD + ks*32 + lg*8);
    bf16x8 t;
    #pragma unroll
    for (int j=0;j<8;j++) t[j] = (short)f2bf(bf2f(v[j])*0.125f);  // 1/sqrt(dk), exact
    aq[ks] = t;
  }

  f32x4 o[4] = {};
  float mrow[4] = {-1e30f,-1e30f,-1e30f,-1e30f};
  float lrow[4] = {0.f,0.f,0.f,0.f};

  for (int kt=0; kt<16; ++kt){
    __syncthreads();
    #pragma unroll
    for (int s2=0; s2<2; ++s2){
      const int slot = tid + s2*256;
      const int row = slot>>3, ch=(slot&7)*8;
      u16x8 vk = *(const u16x8*)(Qb + (size_t)(kt*64+row)*DHEAD + ch);
      u16x8 vv = *(const u16x8*)(Tb + (size_t)row*LTOK + kt*64 + ch);
      const int idx = (row*64+ch) ^ ((row&7)<<3);
      *(u16x8*)(sK+idx) = vk;
      *(u16x8*)(sV+idx) = vv;
    }
    __syncthreads();

    f32x4 sc[4] = {};
    #pragma unroll
    for (int ks=0; ks<2; ++ks){
      #pragma unroll
      for (int nj=0; nj<4; ++nj){
        const int r = nj*16 + lr;
        const int idx = (r*64 + ks*32 + lg*8) ^ ((r&7)<<3);
        bf16x8 bk = *(const bf16x8*)(sK+idx);
        sc[nj] = MFMA16(aq[ks], bk, sc[nj]);
      }
    }

    // online softmax over keys (row lives on the 16 lanes sharing lg)
    #pragma unroll
    for (int r=0; r<4; ++r){
      float t = fmaxf(fmaxf(sc[0][r],sc[1][r]), fmaxf(sc[2][r],sc[3][r]));
      t = fmaxf(t, __shfl_xor(t,1));
      t = fmaxf(t, __shfl_xor(t,2));
      t = fmaxf(t, __shfl_xor(t,4));
      t = fmaxf(t, __shfl_xor(t,8));
      const float mn = fmaxf(mrow[r], t);
      const float c = exp2f((mrow[r]-mn)*1.44269504f);
      mrow[r] = mn;
      float rs = 0.f;
      #pragma unroll
      for (int nj=0; nj<4; ++nj){
        const float p = exp2f((sc[nj][r]-mn)*1.44269504f);
        sc[nj][r] = p; rs += p;
      }
      rs += __shfl_xor(rs,1); rs += __shfl_xor(rs,2);
      rs += __shfl_xor(rs,4); rs += __shfl_xor(rs,8);
      lrow[r] = lrow[r]*c + rs;
      o[0][r]*=c; o[1][r]*=c; o[2][r]*=c; o[3][r]*=c;
    }

    // P -> wave-private LDS rows (bf16, swizzled)
    #pragma unroll
    for (int nj=0; nj<4; ++nj)
      #pragma unroll
      for (int r=0; r<4; ++r){
        const int prow = w*16 + lg*4 + r;
        const int idx = (prow*64 + nj*16 + lr) ^ ((prow&7)<<3);
        sP[idx] = f2bf(sc[nj][r]);
      }
    asm volatile("s_waitcnt lgkmcnt(0)" ::: "memory");

    // PV
    #pragma unroll
    for (int ks=0; ks<2; ++ks){
      const int rA = w*16 + lr;
      const int idxA = (rA*64 + ks*32 + lg*8) ^ ((rA&7)<<3);
      bf16x8 pa = *(const bf16x8*)(sP+idxA);
      #pragma unroll
      for (int dj=0; dj<4; ++dj){
        const int rB = dj*16 + lr;
        const int idxB = (rB*64 + ks*32 + lg*8) ^ ((rB&7)<<3);
        bf16x8 bv = *(const bf16x8*)(sV+idxB);
        o[dj] = MFMA16(pa, bv, o[dj]);
      }
    }
  }

  #pragma unroll
  for (int dj=0; dj<4; ++dj)
    #pragma unroll
    for (int r=0; r<4; ++r){
      const int l = i0 + lg*4 + r;
      const int d = dj*16 + lr;
      const float val = o[dj][r] / lrow[r];
      ao[((size_t)(b*LTOK + l))*DMODEL + h*DHEAD + d] = f2bf(val);
    }
}

// ---------------- FC projection + bias + residual -------------------------------
__global__ __launch_bounds__(256) void fc_gemm(const u16* __restrict__ A,
                                               const u16* __restrict__ W,
                                               const float* __restrict__ bias,
                                               const u16* __restrict__ resid,
                                               u16* __restrict__ Y){
  __shared__ __align__(16) u16 sA[64*64];
  __shared__ __align__(16) u16 sB[64*64];
  const int m0 = blockIdx.x*64, n0 = blockIdx.y*64;
  const int tid = threadIdx.x, w = tid>>6, lane = tid&63;
  const int wr = w>>1, wc = w&1;
  const int lr = lane&15, lg = lane>>4;
  f32x4 acc[2][2] = {};
  for (int kt=0; kt<8; ++kt){
    __syncthreads();
    #pragma unroll
    for (int s2=0; s2<2; ++s2){
      const int slot = tid + s2*256;
      const int row = slot>>3, ch=(slot&7)*8;
      const int k = kt*64 + ch;
      u16x8 va = *(const u16x8*)(A + (size_t)(m0+row)*DMODEL + k);
      u16x8 vb = *(const u16x8*)(W + (size_t)(n0+row)*DMODEL + k);
      const int idx = (row*64 + ch) ^ ((row&7)<<3);
      *(u16x8*)(sA+idx) = va;
      *(u16x8*)(sB+idx) = vb;
    }
    __syncthreads();
    #pragma unroll
    for (int ks=0; ks<2; ++ks){
      bf16x8 af[2], bfr[2];
      #pragma unroll
      for (int mi=0; mi<2; ++mi){
        const int r = wr*32 + mi*16 + lr;
        const int idx = (r*64 + ks*32 + lg*8) ^ ((r&7)<<3);
        af[mi] = *(const bf16x8*)(sA+idx);
      }
      #pragma unroll
      for (int nj=0; nj<2; ++nj){
        const int r = wc*32 + nj*16 + lr;
        const int idx = (r*64 + ks*32 + lg*8) ^ ((r&7)<<3);
        bfr[nj] = *(const bf16x8*)(sB+idx);
      }
      #pragma unroll
      for (int mi=0; mi<2; ++mi)
        #pragma unroll
        for (int nj=0; nj<2; ++nj)
          acc[mi][nj] = MFMA16(af[mi], bfr[nj], acc[mi][nj]);
    }
  }
  #pragma unroll
  for (int mi=0; mi<2; ++mi)
    #pragma unroll
    for (int nj=0; nj<2; ++nj)
      #pragma unroll
      for (int r=0; r<4; ++r){
        const int m = m0 + wr*32 + mi*16 + lg*4 + r;
        const int n = n0 + wc*32 + nj*16 + lr;
        const float val = acc[mi][nj][r] + bias[n] + bf2f(resid[(size_t)m*DMODEL+n]);
        Y[(size_t)m*DMODEL+n] = f2bf(val);
      }
}

// ---------------- LayerNorm over 512, one wave per row; fp32 out ----------------
__global__ __launch_bounds__(256) void ln_k(const u16* __restrict__ Y,
                                            const float* __restrict__ gamma,
                                            const float* __restrict__ beta,
                                            float* __restrict__ out){
  const int row = blockIdx.x*4 + (threadIdx.x>>6);
  const int lane = threadIdx.x&63;
  const u16* yr = Y + (size_t)row*DMODEL;
  u16x8 v = *(const u16x8*)(yr + lane*8);
  float x[8]; float s=0.f, sq=0.f;
  #pragma unroll
  for (int j=0;j<8;j++){ x[j]=bf2f(v[j]); s+=x[j]; sq+=x[j]*x[j]; }
  #pragma unroll
  for (int mk=1; mk<64; mk<<=1){ s += __shfl_xor(s,mk); sq += __shfl_xor(sq,mk); }
  const float mean = s*(1.f/DMODEL);
  float var = sq*(1.f/DMODEL) - mean*mean;
  const float rstd = rsqrtf(var + 1e-5f);
  float* po = out + (size_t)row*DMODEL + lane*8;
  #pragma unroll
  for (int j=0;j<8;j++){
    const int c = lane*8+j;
    po[j] = (x[j]-mean)*rstd*gamma[c] + beta[c];
  }
}

extern "C" void kernel_launch(void* const* d_in, const int* in_sizes, int n_in,
                              void* d_out, int out_size, void* d_ws, size_t ws_size,
                              hipStream_t stream){
  (void)in_sizes; (void)n_in; (void)out_size; (void)ws_size;
  const float* q      = (const float*)d_in[0];
  const float* w_qkvs = (const float*)d_in[1];
  const float* fc_w   = (const float*)d_in[2];
  const float* fc_b   = (const float*)d_in[3];
  const float* ln_g   = (const float*)d_in[4];
  const float* ln_b   = (const float*)d_in[5];
  float* out = (float*)d_out;
  char* ws = (char*)d_ws;
  u16* x_rm  = (u16*)(ws);                 // [8192][512] bf16, 8.39 MB
  u16* qh    = (u16*)(ws + 8388608);       // [64][1024][64]
  u16* qhT   = (u16*)(ws + 16777216);      // [64][64][1024]
  u16* ao    = (u16*)(ws + 25165824);      // [8192][512]
  u16* wqkvb = (u16*)(ws + 33554432);      // [512][512] bf16
  u16* wfcb  = (u16*)(ws + 34078720);      // [512][512] bf16
  u16* y0    = qh;                         // reuse qh region after attention

  // weights fp32 -> bf16
  convert_k<<<128,256,0,stream>>>(w_qkvs, wqkvb, DMODEL*DMODEL);
  convert_k<<<128,256,0,stream>>>(fc_w,   wfcb,  DMODEL*DMODEL);
  // x_rm[b][l][c] = bf16(q[b][c][l])
  transpose_f2b<<<dim3(8,16,BATCH),256,0,stream>>>(q, x_rm, DMODEL, LTOK);
  // qh_rm = x_rm @ w_qkvs^T  (per-head layout)
  qkv_gemm<<<dim3(128,8),256,0,stream>>>(x_rm, wqkvb, qh);
  // qhT[bh][d][l] = qh[bh][l][d]
  transpose_b2b<<<dim3(16,1,64),256,0,stream>>>(qh, qhT, LTOK, DHEAD);
  // attention -> ao[b][l][h*64+d]
  attn_k<<<dim3(16,NHEAD,BATCH),256,0,stream>>>(qh, qhT, ao);
  // y0 = ao @ fc_w^T + fc_b + x_rm
  fc_gemm<<<dim3(128,8),256,0,stream>>>(ao, wfcb, fc_b, x_rm, y0);
  // layernorm -> out (fp32)
  ln_k<<<2048,256,0,stream>>>(y0, ln_g, ln_b, out);
}

// Round 3
// 93.941 us; speedup vs baseline: 1.3046x; 1.3046x over previous
//
#include <hip/hip_runtime.h>
#include <stdint.h>

#define BATCH 8
#define LTOK 1024
#define DMODEL 512
#define NHEAD 8
#define DHEAD 64

typedef unsigned short u16;
typedef u16 u16x8 __attribute__((ext_vector_type(8)));
typedef short bf16x8 __attribute__((ext_vector_type(8)));
typedef float f32x4 __attribute__((ext_vector_type(4)));

#define MFMA16(a,b,c) __builtin_amdgcn_mfma_f32_16x16x32_bf16((a),(b),(c),0,0,0)

__device__ __forceinline__ float bf2f(u16 x){
  union{unsigned u; float f;} v; v.u = ((unsigned)x)<<16; return v.f;
}
__device__ __forceinline__ u16 f2bf(float f){
  union{float f; unsigned u;} v; v.f = f;
  unsigned r = v.u + 0x7fffu + ((v.u>>16)&1u);
  return (u16)(r>>16);
}

// async 8KB tile stage: global (pre-swizzled) -> linear LDS, 16B/lane
__device__ __forceinline__ void stage_tile(const u16* __restrict__ src,
                                           u16* lds, int w, int lane){
  #pragma unroll
  for (int it=0; it<2; ++it){
    const u16* g = src + it*2048 + w*512 + lane*8;
    u16* l = lds + it*2048 + w*512;
    __builtin_amdgcn_global_load_lds(
        (const __attribute__((address_space(1))) void*)g,
        (__attribute__((address_space(3))) void*)l,
        16, 0, 0);
  }
}

// ---------------- fp32 -> bf16 elementwise convert ------------------------------
__global__ __launch_bounds__(256) void convert_k(const float* __restrict__ src,
                                                 u16* __restrict__ dst, int n){
  const int i = (blockIdx.x*256 + threadIdx.x)*8;
  if (i >= n) return;
  u16x8 v;
  #pragma unroll
  for (int j=0;j<8;j++) v[j] = f2bf(src[i+j]);
  *(u16x8*)(dst + i) = v;
}

// ---------------- 64x64 tiled transpose fp32->bf16: dst[c][r] = src[r][c] -------
__global__ __launch_bounds__(256) void transpose_f2b(const float* __restrict__ src,
                                                     u16* __restrict__ dst,
                                                     int R, int C){
  __shared__ __align__(16) u16 t[64][72];
  const int b  = blockIdx.z;
  const int r0 = blockIdx.x*64, c0 = blockIdx.y*64;
  const float* s = src + (size_t)b*R*C;
  u16* d         = dst + (size_t)b*R*C;
  const int tid = threadIdx.x;
  const int row = tid>>3, ch = (tid&7)*8;
  #pragma unroll
  for (int rr=0; rr<64; rr+=32){
    const float* p = s + (size_t)(r0+row+rr)*C + c0 + ch;
    u16x8 v;
    #pragma unroll
    for (int j=0;j<8;j++) v[j] = f2bf(p[j]);
    *(u16x8*)&t[row+rr][ch] = v;
  }
  __syncthreads();
  #pragma unroll
  for (int rr=0; rr<64; rr+=32){
    const int dr = row+rr;
    u16x8 v;
    #pragma unroll
    for (int j=0;j<8;j++) v[j] = t[ch+j][dr];
    *(u16x8*)(d + (size_t)(c0+dr)*R + r0 + ch) = v;
  }
}

// ---------------- per-head tile transpose: qh_sw tile -> vT tile (both swizzled) -
__global__ __launch_bounds__(256) void transpose_vt(const u16* __restrict__ qh,
                                                    u16* __restrict__ vt){
  __shared__ __align__(16) u16 t[64][72];
  const int kt = blockIdx.x, bh = blockIdx.z;
  const u16* src = qh + (size_t)(bh*16 + kt)*4096;
  u16* dst       = vt + (size_t)(bh*16 + kt)*4096;
  const int tid = threadIdx.x;
  const int row = tid>>3, ch = (tid&7)*8;
  #pragma unroll
  for (int rr2=0; rr2<64; rr2+=32){
    const int rr = row + rr2;
    u16x8 v = *(const u16x8*)(src + ((rr*64 + ch) ^ ((rr&7)<<3)));
    *(u16x8*)&t[rr][ch] = v;
  }
  __syncthreads();
  #pragma unroll
  for (int rr2=0; rr2<64; rr2+=32){
    const int d = row + rr2;
    u16x8 v;
    #pragma unroll
    for (int j=0;j<8;j++) v[j] = t[ch+j][d];
    *(u16x8*)(dst + ((d*64 + ch) ^ ((d&7)<<3))) = v;
  }
}

// ---------------- QKV projection -> swizzled per-head 64x64 tiles ---------------
__global__ __launch_bounds__(256) void qkv_gemm(const u16* __restrict__ A,
                                                const u16* __restrict__ W,
                                                u16* __restrict__ qh){
  __shared__ __align__(16) u16 sA[64*64];
  __shared__ __align__(16) u16 sB[64*64];
  const int m0 = blockIdx.x*64, n0 = blockIdx.y*64;
  const int tid = threadIdx.x, w = tid>>6, lane = tid&63;
  const int wr = w>>1, wc = w&1;
  const int lr = lane&15, lg = lane>>4;
  f32x4 acc[2][2] = {};
  for (int kt=0; kt<8; ++kt){
    __syncthreads();
    #pragma unroll
    for (int s2=0; s2<2; ++s2){
      const int slot = tid + s2*256;
      const int row = slot>>3, ch=(slot&7)*8;
      const int k = kt*64 + ch;
      u16x8 va = *(const u16x8*)(A + (size_t)(m0+row)*DMODEL + k);
      u16x8 vb = *(const u16x8*)(W + (size_t)(n0+row)*DMODEL + k);
      const int idx = (row*64 + ch) ^ ((row&7)<<3);
      *(u16x8*)(sA+idx) = va;
      *(u16x8*)(sB+idx) = vb;
    }
    __syncthreads();
    #pragma unroll
    for (int ks=0; ks<2; ++ks){
      bf16x8 af[2], bfr[2];
      #pragma unroll
      for (int mi=0; mi<2; ++mi){
        const int r = wr*32 + mi*16 + lr;
        const int idx = (r*64 + ks*32 + lg*8) ^ ((r&7)<<3);
        af[mi] = *(const bf16x8*)(sA+idx);
      }
      #pragma unroll
      for (int nj=0; nj<2; ++nj){
        const int r = wc*32 + nj*16 + lr;
        const int idx = (r*64 + ks*32 + lg*8) ^ ((r&7)<<3);
        bfr[nj] = *(const bf16x8*)(sB+idx);
      }
      #pragma unroll
      for (int mi=0; mi<2; ++mi)
        #pragma unroll
        for (int nj=0; nj<2; ++nj)
          acc[mi][nj] = MFMA16(af[mi], bfr[nj], acc[mi][nj]);
    }
  }
  #pragma unroll
  for (int mi=0; mi<2; ++mi)
    #pragma unroll
    for (int nj=0; nj<2; ++nj)
      #pragma unroll
      for (int r=0; r<4; ++r){
        const int m = m0 + wr*32 + mi*16 + lg*4 + r;
        const int n = n0 + wc*32 + nj*16 + lr;
        const int bb = m>>10, l = m&1023, hh = n>>6, d = n&63;
        const int bh = bb*NHEAD + hh;
        const int t = l>>6, rr = l&63;
        qh[(size_t)(bh*16 + t)*4096 + ((rr*64 + d) ^ ((rr&7)<<3))] = f2bf(acc[mi][nj][r]);
      }
}

// ---------------- attention: no-max softmax + async double-buffered staging -----
__global__ __launch_bounds__(256) void attn_k(const u16* __restrict__ qh,
                                              const u16* __restrict__ vt,
                                              u16* __restrict__ ao){
  __shared__ __align__(16) u16 sK[2][4096];
  __shared__ __align__(16) u16 sV[2][4096];
  __shared__ __align__(16) u16 sP[4096];
  const int qt = blockIdx.x, h = blockIdx.y, b = blockIdx.z;
  const int bh = b*NHEAD + h;
  const u16* Kb = qh + (size_t)bh*16*4096;
  const u16* Vb = vt + (size_t)bh*16*4096;
  const int tid = threadIdx.x, w = tid>>6, lane = tid&63;
  const int lr = lane&15, lg = lane>>4;

  // Q fragment, scaled by (1/sqrt(dk)) * log2(e) so p = exp2(sc) directly
  bf16x8 aq[2];
  {
    const u16* Qt = Kb + (size_t)qt*4096;
    const int rq = w*16 + lr;
    #pragma unroll
    for (int ks=0; ks<2; ++ks){
      u16x8 v = *(const u16x8*)(Qt + ((rq*64 + ks*32 + lg*8) ^ ((rq&7)<<3)));
      bf16x8 t;
      #pragma unroll
      for (int j=0;j<8;j++) t[j] = (short)f2bf(bf2f(v[j])*0.18033688f);
      aq[ks] = t;
    }
  }

  f32x4 o[4] = {};
  float lsum[4] = {0.f,0.f,0.f,0.f};

  stage_tile(Kb, sK[0], w, lane);
  stage_tile(Vb, sV[0], w, lane);
  __syncthreads();

  int buf = 0;
  for (int kt=0; kt<16; ++kt){
    if (kt+1 < 16){
      stage_tile(Kb + (size_t)(kt+1)*4096, sK[buf^1], w, lane);
      stage_tile(Vb + (size_t)(kt+1)*4096, sV[buf^1], w, lane);
    }
    // QK^T (scores already in log2-units)
    f32x4 sc[4] = {};
    #pragma unroll
    for (int ks=0; ks<2; ++ks){
      #pragma unroll
      for (int nj=0; nj<4; ++nj){
        const int rk = nj*16 + lr;
        bf16x8 bk = *(const bf16x8*)(&sK[buf][(rk*64 + ks*32 + lg*8) ^ ((rk&7)<<3)]);
        sc[nj] = MFMA16(aq[ks], bk, sc[nj]);
      }
    }
    // p = exp2(sc); accumulate per-lane partial row sums; P -> wave-private LDS
    #pragma unroll
    for (int nj=0; nj<4; ++nj){
      #pragma unroll
      for (int r=0; r<4; ++r){
        const float p = exp2f(sc[nj][r]);
        lsum[r] += p;
        const int prow = w*16 + lg*4 + r;
        sP[(prow*64 + nj*16 + lr) ^ ((prow&7)<<3)] = f2bf(p);
      }
    }
    asm volatile("s_waitcnt lgkmcnt(0)" ::: "memory");
    // PV
    #pragma unroll
    for (int ks=0; ks<2; ++ks){
      const int rA = w*16 + lr;
      bf16x8 pa = *(const bf16x8*)(&sP[(rA*64 + ks*32 + lg*8) ^ ((rA&7)<<3)]);
      #pragma unroll
      for (int dj=0; dj<4; ++dj){
        const int rB = dj*16 + lr;
        bf16x8 bv = *(const bf16x8*)(&sV[buf][(rB*64 + ks*32 + lg*8) ^ ((rB&7)<<3)]);
        o[dj] = MFMA16(pa, bv, o[dj]);
      }
    }
    __syncthreads();   // drains prefetch vmcnt + all lds reads of buf
    buf ^= 1;
  }

  // one deferred row-sum reduce across the 16 lanes sharing lg
  #pragma unroll
  for (int r=0; r<4; ++r){
    float s = lsum[r];
    s += __shfl_xor(s,1); s += __shfl_xor(s,2);
    s += __shfl_xor(s,4); s += __shfl_xor(s,8);
    lsum[r] = s;
  }
  const int i0 = qt*64 + w*16;
  #pragma unroll
  for (int dj=0; dj<4; ++dj)
    #pragma unroll
    for (int r=0; r<4; ++r){
      const int l = i0 + lg*4 + r;
      const int d = dj*16 + lr;
      ao[((size_t)(b*LTOK + l))*DMODEL + h*DHEAD + d] = f2bf(o[dj][r]/lsum[r]);
    }
}

// ---------------- FC projection + bias + residual -------------------------------
__global__ __launch_bounds__(256) void fc_gemm(const u16* __restrict__ A,
                                               const u16* __restrict__ W,
                                               const float* __restrict__ bias,
                                               const u16* __restrict__ resid,
                                               u16* __restrict__ Y){
  __shared__ __align__(16) u16 sA[64*64];
  __shared__ __align__(16) u16 sB[64*64];
  const int m0 = blockIdx.x*64, n0 = blockIdx.y*64;
  const int tid = threadIdx.x, w = tid>>6, lane = tid&63;
  const int wr = w>>1, wc = w&1;
  const int lr = lane&15, lg = lane>>4;
  f32x4 acc[2][2] = {};
  for (int kt=0; kt<8; ++kt){
    __syncthreads();
    #pragma unroll
    for (int s2=0; s2<2; ++s2){
      const int slot = tid + s2*256;
      const int row = slot>>3, ch=(slot&7)*8;
      const int k = kt*64 + ch;
      u16x8 va = *(const u16x8*)(A + (size_t)(m0+row)*DMODEL + k);
      u16x8 vb = *(const u16x8*)(W + (size_t)(n0+row)*DMODEL + k);
      const int idx = (row*64 + ch) ^ ((row&7)<<3);
      *(u16x8*)(sA+idx) = va;
      *(u16x8*)(sB+idx) = vb;
    }
    __syncthreads();
    #pragma unroll
    for (int ks=0; ks<2; ++ks){
      bf16x8 af[2], bfr[2];
      #pragma unroll
      for (int mi=0; mi<2; ++mi){
        const int r = wr*32 + mi*16 + lr;
        const int idx = (r*64 + ks*32 + lg*8) ^ ((r&7)<<3);
        af[mi] = *(const bf16x8*)(sA+idx);
      }
      #pragma unroll
      for (int nj=0; nj<2; ++nj){
        const int r = wc*32 + nj*16 + lr;
        const int idx = (r*64 + ks*32 + lg*8) ^ ((r&7)<<3);
        bfr[nj] = *(const bf16x8*)(sB+idx);
      }
      #pragma unroll
      for (int mi=0; mi<2; ++mi)
        #pragma unroll
        for (int nj=0; nj<2; ++nj)
          acc[mi][nj] = MFMA16(af[mi], bfr[nj], acc[mi][nj]);
    }
  }
  #pragma unroll
  for (int mi=0; mi<2; ++mi)
    #pragma unroll
    for (int nj=0; nj<2; ++nj)
      #pragma unroll
      for (int r=0; r<4; ++r){
        const int m = m0 + wr*32 + mi*16 + lg*4 + r;
        const int n = n0 + wc*32 + nj*16 + lr;
        const float val = acc[mi][nj][r] + bias[n] + bf2f(resid[(size_t)m*DMODEL+n]);
        Y[(size_t)m*DMODEL+n] = f2bf(val);
      }
}

// ---------------- LayerNorm over 512, one wave per row; fp32 out ----------------
__global__ __launch_bounds__(256) void ln_k(const u16* __restrict__ Y,
                                            const float* __restrict__ gamma,
                                            const float* __restrict__ beta,
                                            float* __restrict__ out){
  const int row = blockIdx.x*4 + (threadIdx.x>>6);
  const int lane = threadIdx.x&63;
  const u16* yr = Y + (size_t)row*DMODEL;
  u16x8 v = *(const u16x8*)(yr + lane*8);
  float x[8]; float s=0.f, sq=0.f;
  #pragma unroll
  for (int j=0;j<8;j++){ x[j]=bf2f(v[j]); s+=x[j]; sq+=x[j]*x[j]; }
  #pragma unroll
  for (int mk=1; mk<64; mk<<=1){ s += __shfl_xor(s,mk); sq += __shfl_xor(sq,mk); }
  const float mean = s*(1.f/DMODEL);
  float var = sq*(1.f/DMODEL) - mean*mean;
  const float rstd = rsqrtf(var + 1e-5f);
  float* po = out + (size_t)row*DMODEL + lane*8;
  #pragma unroll
  for (int j=0;j<8;j++){
    const int c = lane*8+j;
    po[j] = (x[j]-mean)*rstd*gamma[c] + beta[c];
  }
}

extern "C" void kernel_launch(void* const* d_in, const int* in_sizes, int n_in,
                              void* d_out, int out_size, void* d_ws, size_t ws_size,
                              hipStream_t stream){
  (void)in_sizes; (void)n_in; (void)out_size; (void)ws_size;
  const float* q      = (const float*)d_in[0];
  const float* w_qkvs = (const float*)d_in[1];
  const float* fc_w   = (const float*)d_in[2];
  const float* fc_b   = (const float*)d_in[3];
  const float* ln_g   = (const float*)d_in[4];
  const float* ln_b   = (const float*)d_in[5];
  float* out = (float*)d_out;
  char* ws = (char*)d_ws;
  u16* x_rm  = (u16*)(ws);                 // [8192][512] bf16
  u16* qh_sw = (u16*)(ws + 8388608);       // 64 bh * 16 tiles * 4096, swizzled
  u16* vtt   = (u16*)(ws + 16777216);      // V^T tiles, swizzled
  u16* ao    = (u16*)(ws + 25165824);      // [8192][512]
  u16* wqkvb = (u16*)(ws + 33554432);
  u16* wfcb  = (u16*)(ws + 34078720);
  u16* y0    = qh_sw;                      // reuse after attention

  convert_k<<<128,256,0,stream>>>(w_qkvs, wqkvb, DMODEL*DMODEL);
  convert_k<<<128,256,0,stream>>>(fc_w,   wfcb,  DMODEL*DMODEL);
  transpose_f2b<<<dim3(8,16,BATCH),256,0,stream>>>(q, x_rm, DMODEL, LTOK);
  qkv_gemm<<<dim3(128,8),256,0,stream>>>(x_rm, wqkvb, qh_sw);
  transpose_vt<<<dim3(16,1,64),256,0,stream>>>(qh_sw, vtt);
  attn_k<<<dim3(16,NHEAD,BATCH),256,0,stream>>>(qh_sw, vtt, ao);
  fc_gemm<<<dim3(128,8),256,0,stream>>>(ao, wfcb, fc_b, x_rm, y0);
  ln_k<<<2048,256,0,stream>>>(y0, ln_g, ln_b, out);
}

// Round 5
// 86.526 us; speedup vs baseline: 1.4164x; 1.0857x over previous
//
#include <hip/hip_runtime.h>
#include <stdint.h>

#define BATCH 8
#define LTOK 1024
#define DMODEL 512
#define NHEAD 8
#define DHEAD 64

typedef unsigned short u16;
typedef u16 u16x8 __attribute__((ext_vector_type(8)));
typedef short bf16x8 __attribute__((ext_vector_type(8)));
typedef float f32x4 __attribute__((ext_vector_type(4)));

#define MFMA16(a,b,c) __builtin_amdgcn_mfma_f32_16x16x32_bf16((a),(b),(c),0,0,0)

__device__ __forceinline__ float bf2f(u16 x){
  union{unsigned u; float f;} v; v.u = ((unsigned)x)<<16; return v.f;
}
__device__ __forceinline__ u16 f2bf(float f){
  union{float f; unsigned u;} v; v.f = f;
  unsigned r = v.u + 0x7fffu + ((v.u>>16)&1u);
  return (u16)(r>>16);
}

// async 8KB tile stage: global (pre-swizzled) -> linear LDS, 16B/lane
__device__ __forceinline__ void stage_tile(const u16* __restrict__ src,
                                           u16* lds, int w, int lane){
  #pragma unroll
  for (int it=0; it<2; ++it){
    const u16* g = src + it*2048 + w*512 + lane*8;
    u16* l = lds + it*2048 + w*512;
    __builtin_amdgcn_global_load_lds(
        (const __attribute__((address_space(1))) void*)g,
        (__attribute__((address_space(3))) void*)l,
        16, 0, 0);
  }
}

// ---------------- fp32 -> bf16 elementwise convert ------------------------------
__global__ __launch_bounds__(256) void convert_k(const float* __restrict__ src,
                                                 u16* __restrict__ dst, int n){
  const int i = (blockIdx.x*256 + threadIdx.x)*8;
  if (i >= n) return;
  u16x8 v;
  #pragma unroll
  for (int j=0;j<8;j++) v[j] = f2bf(src[i+j]);
  *(u16x8*)(dst + i) = v;
}

// ---------------- 64x64 tiled transpose fp32->bf16: dst[c][r] = src[r][c] -------
__global__ __launch_bounds__(256) void transpose_f2b(const float* __restrict__ src,
                                                     u16* __restrict__ dst,
                                                     int R, int C){
  __shared__ __align__(16) u16 t[64][72];
  const int b  = blockIdx.z;
  const int r0 = blockIdx.x*64, c0 = blockIdx.y*64;
  const float* s = src + (size_t)b*R*C;
  u16* d         = dst + (size_t)b*R*C;
  const int tid = threadIdx.x;
  const int row = tid>>3, ch = (tid&7)*8;
  #pragma unroll
  for (int rr=0; rr<64; rr+=32){
    const float* p = s + (size_t)(r0+row+rr)*C + c0 + ch;
    u16x8 v;
    #pragma unroll
    for (int j=0;j<8;j++) v[j] = f2bf(p[j]);
    *(u16x8*)&t[row+rr][ch] = v;
  }
  __syncthreads();
  #pragma unroll
  for (int rr=0; rr<64; rr+=32){
    const int dr = row+rr;
    u16x8 v;
    #pragma unroll
    for (int j=0;j<8;j++) v[j] = t[ch+j][dr];
    *(u16x8*)(d + (size_t)(c0+dr)*R + r0 + ch) = v;
  }
}

// ---------------- QKV projection -> swizzled per-head tiles (qh AND v^T) --------
__global__ __launch_bounds__(256) void qkv_gemm(const u16* __restrict__ A,
                                                const u16* __restrict__ W,
                                                u16* __restrict__ qh,
                                                u16* __restrict__ vt){
  __shared__ __align__(16) u16 sA[64*64];
  __shared__ __align__(16) u16 sB[64*64];
  const int m0 = blockIdx.x*64, n0 = blockIdx.y*64;
  const int tid = threadIdx.x, w = tid>>6, lane = tid&63;
  const int wr = w>>1, wc = w&1;
  const int lr = lane&15, lg = lane>>4;
  f32x4 acc[2][2] = {};
  for (int kt=0; kt<8; ++kt){
    __syncthreads();
    #pragma unroll
    for (int s2=0; s2<2; ++s2){
      const int slot = tid + s2*256;
      const int row = slot>>3, ch=(slot&7)*8;
      const int k = kt*64 + ch;
      u16x8 va = *(const u16x8*)(A + (size_t)(m0+row)*DMODEL + k);
      u16x8 vb = *(const u16x8*)(W + (size_t)(n0+row)*DMODEL + k);
      const int idx = (row*64 + ch) ^ ((row&7)<<3);
      *(u16x8*)(sA+idx) = va;
      *(u16x8*)(sB+idx) = vb;
    }
    __syncthreads();
    #pragma unroll
    for (int ks=0; ks<2; ++ks){
      bf16x8 af[2], bfr[2];
      #pragma unroll
      for (int mi=0; mi<2; ++mi){
        const int r = wr*32 + mi*16 + lr;
        const int idx = (r*64 + ks*32 + lg*8) ^ ((r&7)<<3);
        af[mi] = *(const bf16x8*)(sA+idx);
      }
      #pragma unroll
      for (int nj=0; nj<2; ++nj){
        const int r = wc*32 + nj*16 + lr;
        const int idx = (r*64 + ks*32 + lg*8) ^ ((r&7)<<3);
        bfr[nj] = *(const bf16x8*)(sB+idx);
      }
      #pragma unroll
      for (int mi=0; mi<2; ++mi)
        #pragma unroll
        for (int nj=0; nj<2; ++nj)
          acc[mi][nj] = MFMA16(af[mi], bfr[nj], acc[mi][nj]);
    }
  }
  #pragma unroll
  for (int mi=0; mi<2; ++mi)
    #pragma unroll
    for (int nj=0; nj<2; ++nj)
      #pragma unroll
      for (int r=0; r<4; ++r){
        const int m = m0 + wr*32 + mi*16 + lg*4 + r;
        const int n = n0 + wc*32 + nj*16 + lr;
        const int bb = m>>10, l = m&1023, hh = n>>6, d = n&63;
        const int bh = bb*NHEAD + hh;
        const int t = l>>6, rr = l&63;
        const u16 val = f2bf(acc[mi][nj][r]);
        qh[(size_t)(bh*16 + t)*4096 + ((rr*64 + d) ^ ((rr&7)<<3))] = val;
        vt[(size_t)(bh*16 + t)*4096 + ((d*64 + rr) ^ ((d&7)<<3))]  = val;
      }
}

// ---------------- attention: no-max softmax, XCD-grouped, proven PV path --------
__global__ __launch_bounds__(256) void attn_k(const u16* __restrict__ qh,
                                              const u16* __restrict__ vt,
                                              u16* __restrict__ ao){
  __shared__ __align__(128) u16 sK[2][4096];
  __shared__ __align__(128) u16 sV[2][4096];
  __shared__ __align__(128) u16 sP[4096];
  const int bid = blockIdx.x;
  const int qt = bid >> 6, bh = bid & 63;   // XCD = bid%8 = bh%8 -> K/V L2-resident
  const int b = bh >> 3, h = bh & 7;
  const u16* Kb = qh + (size_t)bh*16*4096;
  const u16* Vb = vt + (size_t)bh*16*4096;
  const int tid = threadIdx.x, w = tid>>6, lane = tid&63;
  const int lr = lane&15, lg = lane>>4;

  // Q fragment, scaled by (1/sqrt(dk)) * log2(e) so p = exp2(sc) directly
  bf16x8 aq[2];
  {
    const u16* Qt = Kb + (size_t)qt*4096;
    const int rq = w*16 + lr;
    #pragma unroll
    for (int ks=0; ks<2; ++ks){
      u16x8 v = *(const u16x8*)(Qt + ((rq*64 + ks*32 + lg*8) ^ ((rq&7)<<3)));
      bf16x8 t;
      #pragma unroll
      for (int j=0;j<8;j++) t[j] = (short)f2bf(bf2f(v[j])*0.18033688f);
      aq[ks] = t;
    }
  }

  f32x4 o[4] = {};
  float lsum[4] = {0.f,0.f,0.f,0.f};

  stage_tile(Kb, sK[0], w, lane);
  stage_tile(Vb, sV[0], w, lane);
  __syncthreads();

  int buf = 0;
  for (int kt=0; kt<16; ++kt){
    if (kt+1 < 16){
      stage_tile(Kb + (size_t)(kt+1)*4096, sK[buf^1], w, lane);
      stage_tile(Vb + (size_t)(kt+1)*4096, sV[buf^1], w, lane);
    }
    // QK^T (scores already in log2-units)
    f32x4 sc[4] = {};
    #pragma unroll
    for (int ks=0; ks<2; ++ks){
      #pragma unroll
      for (int nj=0; nj<4; ++nj){
        const int rk = nj*16 + lr;
        bf16x8 bk = *(const bf16x8*)(&sK[buf][(rk*64 + ks*32 + lg*8) ^ ((rk&7)<<3)]);
        sc[nj] = MFMA16(aq[ks], bk, sc[nj]);
      }
    }
    // p = exp2(sc), truncate to bf16 (sum the SAME truncated value -> no bias)
    #pragma unroll
    for (int nj=0; nj<4; ++nj){
      #pragma unroll
      for (int r=0; r<4; ++r){
        const float p = __builtin_amdgcn_exp2f(sc[nj][r]);
        const unsigned pu = __float_as_uint(p) & 0xFFFF0000u;
        lsum[r] += __uint_as_float(pu);
        const int prow = w*16 + lg*4 + r;
        sP[(prow*64 + nj*16 + lr) ^ ((prow&7)<<3)] = (u16)(pu>>16);
      }
    }
    asm volatile("s_waitcnt lgkmcnt(0)" ::: "memory");
    // PV (proven b128 path)
    #pragma unroll
    for (int ks=0; ks<2; ++ks){
      const int rA = w*16 + lr;
      bf16x8 pa = *(const bf16x8*)(&sP[(rA*64 + ks*32 + lg*8) ^ ((rA&7)<<3)]);
      #pragma unroll
      for (int dj=0; dj<4; ++dj){
        const int rB = dj*16 + lr;
        bf16x8 bv = *(const bf16x8*)(&sV[buf][(rB*64 + ks*32 + lg*8) ^ ((rB&7)<<3)]);
        o[dj] = MFMA16(pa, bv, o[dj]);
      }
    }
    __syncthreads();   // drains prefetch vmcnt + all lds reads of buf
    buf ^= 1;
  }

  // one deferred row-sum reduce across the 16 lanes sharing lg
  float inv[4];
  #pragma unroll
  for (int r=0; r<4; ++r){
    float s = lsum[r];
    s += __shfl_xor(s,1); s += __shfl_xor(s,2);
    s += __shfl_xor(s,4); s += __shfl_xor(s,8);
    inv[r] = __builtin_amdgcn_rcpf(s);
  }
  const int i0 = qt*64 + w*16;
  #pragma unroll
  for (int dj=0; dj<4; ++dj)
    #pragma unroll
    for (int r=0; r<4; ++r){
      const int l = i0 + lg*4 + r;
      const int d = dj*16 + lr;
      ao[((size_t)(b*LTOK + l))*DMODEL + h*DHEAD + d] = f2bf(o[dj][r]*inv[r]);
    }
}

// ---------------- FC projection + bias + residual -------------------------------
__global__ __launch_bounds__(256) void fc_gemm(const u16* __restrict__ A,
                                               const u16* __restrict__ W,
                                               const float* __restrict__ bias,
                                               const u16* __restrict__ resid,
                                               u16* __restrict__ Y){
  __shared__ __align__(16) u16 sA[64*64];
  __shared__ __align__(16) u16 sB[64*64];
  const int m0 = blockIdx.x*64, n0 = blockIdx.y*64;
  const int tid = threadIdx.x, w = tid>>6, lane = tid&63;
  const int wr = w>>1, wc = w&1;
  const int lr = lane&15, lg = lane>>4;
  f32x4 acc[2][2] = {};
  for (int kt=0; kt<8; ++kt){
    __syncthreads();
    #pragma unroll
    for (int s2=0; s2<2; ++s2){
      const int slot = tid + s2*256;
      const int row = slot>>3, ch=(slot&7)*8;
      const int k = kt*64 + ch;
      u16x8 va = *(const u16x8*)(A + (size_t)(m0+row)*DMODEL + k);
      u16x8 vb = *(const u16x8*)(W + (size_t)(n0+row)*DMODEL + k);
      const int idx = (row*64 + ch) ^ ((row&7)<<3);
      *(u16x8*)(sA+idx) = va;
      *(u16x8*)(sB+idx) = vb;
    }
    __syncthreads();
    #pragma unroll
    for (int ks=0; ks<2; ++ks){
      bf16x8 af[2], bfr[2];
      #pragma unroll
      for (int mi=0; mi<2; ++mi){
        const int r = wr*32 + mi*16 + lr;
        const int idx = (r*64 + ks*32 + lg*8) ^ ((r&7)<<3);
        af[mi] = *(const bf16x8*)(sA+idx);
      }
      #pragma unroll
      for (int nj=0; nj<2; ++nj){
        const int r = wc*32 + nj*16 + lr;
        const int idx = (r*64 + ks*32 + lg*8) ^ ((r&7)<<3);
        bfr[nj] = *(const bf16x8*)(sB+idx);
      }
      #pragma unroll
      for (int mi=0; mi<2; ++mi)
        #pragma unroll
        for (int nj=0; nj<2; ++nj)
          acc[mi][nj] = MFMA16(af[mi], bfr[nj], acc[mi][nj]);
    }
  }
  #pragma unroll
  for (int mi=0; mi<2; ++mi)
    #pragma unroll
    for (int nj=0; nj<2; ++nj)
      #pragma unroll
      for (int r=0; r<4; ++r){
        const int m = m0 + wr*32 + mi*16 + lg*4 + r;
        const int n = n0 + wc*32 + nj*16 + lr;
        const float val = acc[mi][nj][r] + bias[n] + bf2f(resid[(size_t)m*DMODEL+n]);
        Y[(size_t)m*DMODEL+n] = f2bf(val);
      }
}

// ---------------- LayerNorm over 512, one wave per row; fp32 out ----------------
__global__ __launch_bounds__(256) void ln_k(const u16* __restrict__ Y,
                                            const float* __restrict__ gamma,
                                            const float* __restrict__ beta,
                                            float* __restrict__ out){
  const int row = blockIdx.x*4 + (threadIdx.x>>6);
  const int lane = threadIdx.x&63;
  const u16* yr = Y + (size_t)row*DMODEL;
  u16x8 v = *(const u16x8*)(yr + lane*8);
  float x[8]; float s=0.f, sq=0.f;
  #pragma unroll
  for (int j=0;j<8;j++){ x[j]=bf2f(v[j]); s+=x[j]; sq+=x[j]*x[j]; }
  #pragma unroll
  for (int mk=1; mk<64; mk<<=1){ s += __shfl_xor(s,mk); sq += __shfl_xor(sq,mk); }
  const float mean = s*(1.f/DMODEL);
  float var = sq*(1.f/DMODEL) - mean*mean;
  const float rstd = rsqrtf(var + 1e-5f);
  float* po = out + (size_t)row*DMODEL + lane*8;
  #pragma unroll
  for (int j=0;j<8;j++){
    const int c = lane*8+j;
    po[j] = (x[j]-mean)*rstd*gamma[c] + beta[c];
  }
}

extern "C" void kernel_launch(void* const* d_in, const int* in_sizes, int n_in,
                              void* d_out, int out_size, void* d_ws, size_t ws_size,
                              hipStream_t stream){
  (void)in_sizes; (void)n_in; (void)out_size; (void)ws_size;
  const float* q      = (const float*)d_in[0];
  const float* w_qkvs = (const float*)d_in[1];
  const float* fc_w   = (const float*)d_in[2];
  const float* fc_b   = (const float*)d_in[3];
  const float* ln_g   = (const float*)d_in[4];
  const float* ln_b   = (const float*)d_in[5];
  float* out = (float*)d_out;
  char* ws = (char*)d_ws;
  u16* x_rm  = (u16*)(ws);                 // [8192][512] bf16
  u16* qh_sw = (u16*)(ws + 8388608);       // 64 bh * 16 tiles * 4096, swizzled
  u16* vtt   = (u16*)(ws + 16777216);      // V^T tiles, swizzled
  u16* ao    = (u16*)(ws + 25165824);      // [8192][512]
  u16* wqkvb = (u16*)(ws + 33554432);
  u16* wfcb  = (u16*)(ws + 34078720);
  u16* y0    = qh_sw;                      // reuse after attention

  convert_k<<<128,256,0,stream>>>(w_qkvs, wqkvb, DMODEL*DMODEL);
  convert_k<<<128,256,0,stream>>>(fc_w,   wfcb,  DMODEL*DMODEL);
  transpose_f2b<<<dim3(8,16,BATCH),256,0,stream>>>(q, x_rm, DMODEL, LTOK);
  qkv_gemm<<<dim3(128,8),256,0,stream>>>(x_rm, wqkvb, qh_sw, vtt);
  attn_k<<<1024,256,0,stream>>>(qh_sw, vtt, ao);
  fc_gemm<<<dim3(128,8),256,0,stream>>>(ao, wfcb, fc_b, x_rm, y0);
  ln_k<<<2048,256,0,stream>>>(y0, ln_g, ln_b, out);
}

// Round 6
// 81.682 us; speedup vs baseline: 1.5004x; 1.0593x over previous
//
#include <hip/hip_runtime.h>
#include <stdint.h>

#define BATCH 8
#define LTOK 1024
#define DMODEL 512
#define NHEAD 8
#define DHEAD 64

typedef unsigned short u16;
typedef u16 u16x8 __attribute__((ext_vector_type(8)));
typedef short bf16x8 __attribute__((ext_vector_type(8)));
typedef float f32x4 __attribute__((ext_vector_type(4)));

#define MFMA16(a,b,c) __builtin_amdgcn_mfma_f32_16x16x32_bf16((a),(b),(c),0,0,0)

__device__ __forceinline__ float bf2f(u16 x){
  union{unsigned u; float f;} v; v.u = ((unsigned)x)<<16; return v.f;
}
__device__ __forceinline__ u16 f2bf(float f){
  union{float f; unsigned u;} v; v.f = f;
  unsigned r = v.u + 0x7fffu + ((v.u>>16)&1u);
  return (u16)(r>>16);
}

__device__ __forceinline__ void gload_lds16(const u16* g, u16* l){
  __builtin_amdgcn_global_load_lds(
      (const __attribute__((address_space(1))) void*)g,
      (__attribute__((address_space(3))) void*)l,
      16, 0, 0);
}

// ---------------- fp32 -> bf16 elementwise convert ------------------------------
__global__ __launch_bounds__(256) void convert_k(const float* __restrict__ src,
                                                 u16* __restrict__ dst, int n){
  const int i = (blockIdx.x*256 + threadIdx.x)*8;
  if (i >= n) return;
  u16x8 v;
  #pragma unroll
  for (int j=0;j<8;j++) v[j] = f2bf(src[i+j]);
  *(u16x8*)(dst + i) = v;
}

// ---------------- 64x64 tiled transpose fp32->bf16: dst[c][r] = src[r][c] -------
__global__ __launch_bounds__(256) void transpose_f2b(const float* __restrict__ src,
                                                     u16* __restrict__ dst,
                                                     int R, int C){
  __shared__ __align__(16) u16 t[64][72];
  const int b  = blockIdx.z;
  const int r0 = blockIdx.x*64, c0 = blockIdx.y*64;
  const float* s = src + (size_t)b*R*C;
  u16* d         = dst + (size_t)b*R*C;
  const int tid = threadIdx.x;
  const int row = tid>>3, ch = (tid&7)*8;
  #pragma unroll
  for (int rr=0; rr<64; rr+=32){
    const float* p = s + (size_t)(r0+row+rr)*C + c0 + ch;
    u16x8 v;
    #pragma unroll
    for (int j=0;j<8;j++) v[j] = f2bf(p[j]);
    *(u16x8*)&t[row+rr][ch] = v;
  }
  __syncthreads();
  #pragma unroll
  for (int rr=0; rr<64; rr+=32){
    const int dr = row+rr;
    u16x8 v;
    #pragma unroll
    for (int j=0;j<8;j++) v[j] = t[ch+j][dr];
    *(u16x8*)(d + (size_t)(c0+dr)*R + r0 + ch) = v;
  }
}

// stage a 64x64 bf16 tile into linear LDS with the read-swizzle pre-applied to
// the source k-chunk (rule 21: filler granule (r, cc^(r&7)) holds A[r][cc*8])
__device__ __forceinline__ void stage_gemm(const u16* __restrict__ src,
                                           int row0, int k0, u16* lds, int tid){
  #pragma unroll
  for (int s2=0; s2<2; ++s2){
    const int slot = tid + s2*256;
    const int row = slot>>3, ch8 = slot&7;
    const int k = k0 + ((ch8 ^ (row&7))<<3);
    gload_lds16(src + (size_t)(row0+row)*DMODEL + k, lds + slot*8);
  }
}

// ---------------- QKV projection -> swizzled per-head tiles (qh AND v^T) --------
__global__ __launch_bounds__(256) void qkv_gemm(const u16* __restrict__ A,
                                                const u16* __restrict__ W,
                                                u16* __restrict__ qh,
                                                u16* __restrict__ vt){
  __shared__ __align__(128) u16 sA[2][4096];
  __shared__ __align__(128) u16 sB[2][4096];
  const int m0 = blockIdx.x*64, n0 = blockIdx.y*64;
  const int tid = threadIdx.x, w = tid>>6, lane = tid&63;
  const int wr = w>>1, wc = w&1;
  const int lr = lane&15, lg = lane>>4;
  f32x4 acc[2][2] = {};
  stage_gemm(A, m0, 0, sA[0], tid);
  stage_gemm(W, n0, 0, sB[0], tid);
  int buf = 0;
  for (int kt=0; kt<8; ++kt){
    __syncthreads();
    if (kt < 7){
      stage_gemm(A, m0, (kt+1)*64, sA[buf^1], tid);
      stage_gemm(W, n0, (kt+1)*64, sB[buf^1], tid);
    }
    #pragma unroll
    for (int ks=0; ks<2; ++ks){
      bf16x8 af[2], bfr[2];
      #pragma unroll
      for (int mi=0; mi<2; ++mi){
        const int r = wr*32 + mi*16 + lr;
        af[mi] = *(const bf16x8*)(&sA[buf][(r*64 + ks*32 + lg*8) ^ ((r&7)<<3)]);
      }
      #pragma unroll
      for (int nj=0; nj<2; ++nj){
        const int r = wc*32 + nj*16 + lr;
        bfr[nj] = *(const bf16x8*)(&sB[buf][(r*64 + ks*32 + lg*8) ^ ((r&7)<<3)]);
      }
      #pragma unroll
      for (int mi=0; mi<2; ++mi)
        #pragma unroll
        for (int nj=0; nj<2; ++nj)
          acc[mi][nj] = MFMA16(af[mi], bfr[nj], acc[mi][nj]);
    }
    buf ^= 1;
  }
  #pragma unroll
  for (int mi=0; mi<2; ++mi)
    #pragma unroll
    for (int nj=0; nj<2; ++nj)
      #pragma unroll
      for (int r=0; r<4; ++r){
        const int m = m0 + wr*32 + mi*16 + lg*4 + r;
        const int n = n0 + wc*32 + nj*16 + lr;
        const int bb = m>>10, l = m&1023, hh = n>>6, d = n&63;
        const int bh = bb*NHEAD + hh;
        const int t = l>>6, rr = l&63;
        const u16 val = f2bf(acc[mi][nj][r]);
        qh[(size_t)(bh*16 + t)*4096 + ((rr*64 + d) ^ ((rr&7)<<3))] = val;
        vt[(size_t)(bh*16 + t)*4096 + ((d*64 + rr) ^ ((d&7)<<3))]  = val;
      }
}

// ---------------- attention: QBLK=128, 8 waves, no-max softmax, XCD-grouped -----
__global__ __launch_bounds__(512) void attn_k(const u16* __restrict__ qh,
                                              const u16* __restrict__ vt,
                                              u16* __restrict__ ao){
  __shared__ __align__(128) u16 sK[2][4096];
  __shared__ __align__(128) u16 sV[2][4096];
  __shared__ __align__(128) u16 sP[8192];
  const int bid = blockIdx.x;
  const int qt = bid >> 6, bh = bid & 63;   // XCD = bid%8 = bh%8 -> K/V L2-resident
  const int b = bh >> 3, h = bh & 7;
  const u16* Kb = qh + (size_t)bh*16*4096;
  const u16* Vb = vt + (size_t)bh*16*4096;
  const int tid = threadIdx.x, w = tid>>6, lane = tid&63;
  const int lr = lane&15, lg = lane>>4;
  const int wp = w*1024;                    // wave-private P region (u16 units)

  // Q fragment: rows qt*128 + w*16 + [0,16); scaled by (1/8)*log2(e)
  bf16x8 aq[2];
  {
    const u16* Qt = Kb + (size_t)(qt*2 + (w>>2))*4096;
    const int rq = (w&3)*16 + lr;
    #pragma unroll
    for (int ks=0; ks<2; ++ks){
      u16x8 v = *(const u16x8*)(Qt + ((rq*64 + ks*32 + lg*8) ^ ((rq&7)<<3)));
      bf16x8 t;
      #pragma unroll
      for (int j=0;j<8;j++) t[j] = (short)f2bf(bf2f(v[j])*0.18033688f);
      aq[ks] = t;
    }
  }

  f32x4 o[4] = {};
  float lsum[4] = {0.f,0.f,0.f,0.f};

  // stage: 512 threads x 16B = one 8KB tile per call
  gload_lds16(Kb + tid*8, sK[0] + tid*8);
  gload_lds16(Vb + tid*8, sV[0] + tid*8);
  __syncthreads();

  int buf = 0;
  for (int kt=0; kt<16; ++kt){
    if (kt+1 < 16){
      gload_lds16(Kb + (size_t)(kt+1)*4096 + tid*8, sK[buf^1] + tid*8);
      gload_lds16(Vb + (size_t)(kt+1)*4096 + tid*8, sV[buf^1] + tid*8);
    }
    // QK^T (scores already in log2-units)
    f32x4 sc[4] = {};
    #pragma unroll
    for (int ks=0; ks<2; ++ks){
      #pragma unroll
      for (int nj=0; nj<4; ++nj){
        const int rk = nj*16 + lr;
        bf16x8 bk = *(const bf16x8*)(&sK[buf][(rk*64 + ks*32 + lg*8) ^ ((rk&7)<<3)]);
        sc[nj] = MFMA16(aq[ks], bk, sc[nj]);
      }
    }
    // p = exp2(sc), truncate to bf16 (sum the SAME truncated value -> no bias)
    #pragma unroll
    for (int nj=0; nj<4; ++nj){
      #pragma unroll
      for (int r=0; r<4; ++r){
        const float p = __builtin_amdgcn_exp2f(sc[nj][r]);
        const unsigned pu = __float_as_uint(p) & 0xFFFF0000u;
        lsum[r] += __uint_as_float(pu);
        const int prow = lg*4 + r;
        sP[wp + ((prow*64 + nj*16 + lr) ^ ((prow&7)<<3))] = (u16)(pu>>16);
      }
    }
    asm volatile("s_waitcnt lgkmcnt(0)" ::: "memory");
    // PV
    #pragma unroll
    for (int ks=0; ks<2; ++ks){
      bf16x8 pa = *(const bf16x8*)(&sP[wp + ((lr*64 + ks*32 + lg*8) ^ ((lr&7)<<3))]);
      #pragma unroll
      for (int dj=0; dj<4; ++dj){
        const int rB = dj*16 + lr;
        bf16x8 bv = *(const bf16x8*)(&sV[buf][(rB*64 + ks*32 + lg*8) ^ ((rB&7)<<3)]);
        o[dj] = MFMA16(pa, bv, o[dj]);
      }
    }
    __syncthreads();   // drains prefetch vmcnt + all lds reads of buf
    buf ^= 1;
  }

  // one deferred row-sum reduce across the 16 lanes sharing lg
  float inv[4];
  #pragma unroll
  for (int r=0; r<4; ++r){
    float s = lsum[r];
    s += __shfl_xor(s,1); s += __shfl_xor(s,2);
    s += __shfl_xor(s,4); s += __shfl_xor(s,8);
    inv[r] = __builtin_amdgcn_rcpf(s);
  }
  const int i0 = qt*128 + w*16;
  #pragma unroll
  for (int dj=0; dj<4; ++dj)
    #pragma unroll
    for (int r=0; r<4; ++r){
      const int l = i0 + lg*4 + r;
      const int d = dj*16 + lr;
      ao[((size_t)(b*LTOK + l))*DMODEL + h*DHEAD + d] = f2bf(o[dj][r]*inv[r]);
    }
}

// ---------------- FC projection + bias + residual -------------------------------
__global__ __launch_bounds__(256) void fc_gemm(const u16* __restrict__ A,
                                               const u16* __restrict__ W,
                                               const float* __restrict__ bias,
                                               const u16* __restrict__ resid,
                                               u16* __restrict__ Y){
  __shared__ __align__(128) u16 sA[2][4096];
  __shared__ __align__(128) u16 sB[2][4096];
  const int m0 = blockIdx.x*64, n0 = blockIdx.y*64;
  const int tid = threadIdx.x, w = tid>>6, lane = tid&63;
  const int wr = w>>1, wc = w&1;
  const int lr = lane&15, lg = lane>>4;
  f32x4 acc[2][2] = {};
  stage_gemm(A, m0, 0, sA[0], tid);
  stage_gemm(W, n0, 0, sB[0], tid);
  int buf = 0;
  for (int kt=0; kt<8; ++kt){
    __syncthreads();
    if (kt < 7){
      stage_gemm(A, m0, (kt+1)*64, sA[buf^1], tid);
      stage_gemm(W, n0, (kt+1)*64, sB[buf^1], tid);
    }
    #pragma unroll
    for (int ks=0; ks<2; ++ks){
      bf16x8 af[2], bfr[2];
      #pragma unroll
      for (int mi=0; mi<2; ++mi){
        const int r = wr*32 + mi*16 + lr;
        af[mi] = *(const bf16x8*)(&sA[buf][(r*64 + ks*32 + lg*8) ^ ((r&7)<<3)]);
      }
      #pragma unroll
      for (int nj=0; nj<2; ++nj){
        const int r = wc*32 + nj*16 + lr;
        bfr[nj] = *(const bf16x8*)(&sB[buf][(r*64 + ks*32 + lg*8) ^ ((r&7)<<3)]);
      }
      #pragma unroll
      for (int mi=0; mi<2; ++mi)
        #pragma unroll
        for (int nj=0; nj<2; ++nj)
          acc[mi][nj] = MFMA16(af[mi], bfr[nj], acc[mi][nj]);
    }
    buf ^= 1;
  }
  #pragma unroll
  for (int mi=0; mi<2; ++mi)
    #pragma unroll
    for (int nj=0; nj<2; ++nj)
      #pragma unroll
      for (int r=0; r<4; ++r){
        const int m = m0 + wr*32 + mi*16 + lg*4 + r;
        const int n = n0 + wc*32 + nj*16 + lr;
        const float val = acc[mi][nj][r] + bias[n] + bf2f(resid[(size_t)m*DMODEL+n]);
        Y[(size_t)m*DMODEL+n] = f2bf(val);
      }
}

// ---------------- LayerNorm over 512, one wave per row; fp32 out ----------------
__global__ __launch_bounds__(256) void ln_k(const u16* __restrict__ Y,
                                            const float* __restrict__ gamma,
                                            const float* __restrict__ beta,
                                            float* __restrict__ out){
  const int row = blockIdx.x*4 + (threadIdx.x>>6);
  const int lane = threadIdx.x&63;
  const u16* yr = Y + (size_t)row*DMODEL;
  u16x8 v = *(const u16x8*)(yr + lane*8);
  float x[8]; float s=0.f, sq=0.f;
  #pragma unroll
  for (int j=0;j<8;j++){ x[j]=bf2f(v[j]); s+=x[j]; sq+=x[j]*x[j]; }
  #pragma unroll
  for (int mk=1; mk<64; mk<<=1){ s += __shfl_xor(s,mk); sq += __shfl_xor(sq,mk); }
  const float mean = s*(1.f/DMODEL);
  float var = sq*(1.f/DMODEL) - mean*mean;
  const float rstd = rsqrtf(var + 1e-5f);
  float* po = out + (size_t)row*DMODEL + lane*8;
  #pragma unroll
  for (int j=0;j<8;j++){
    const int c = lane*8+j;
    po[j] = (x[j]-mean)*rstd*gamma[c] + beta[c];
  }
}

extern "C" void kernel_launch(void* const* d_in, const int* in_sizes, int n_in,
                              void* d_out, int out_size, void* d_ws, size_t ws_size,
                              hipStream_t stream){
  (void)in_sizes; (void)n_in; (void)out_size; (void)ws_size;
  const float* q      = (const float*)d_in[0];
  const float* w_qkvs = (const float*)d_in[1];
  const float* fc_w   = (const float*)d_in[2];
  const float* fc_b   = (const float*)d_in[3];
  const float* ln_g   = (const float*)d_in[4];
  const float* ln_b   = (const float*)d_in[5];
  float* out = (float*)d_out;
  char* ws = (char*)d_ws;
  u16* x_rm  = (u16*)(ws);                 // [8192][512] bf16
  u16* qh_sw = (u16*)(ws + 8388608);       // 64 bh * 16 tiles * 4096, swizzled
  u16* vtt   = (u16*)(ws + 16777216);      // V^T tiles, swizzled
  u16* ao    = (u16*)(ws + 25165824);      // [8192][512]
  u16* wqkvb = (u16*)(ws + 33554432);
  u16* wfcb  = (u16*)(ws + 34078720);
  u16* y0    = qh_sw;                      // reuse after attention

  convert_k<<<128,256,0,stream>>>(w_qkvs, wqkvb, DMODEL*DMODEL);
  convert_k<<<128,256,0,stream>>>(fc_w,   wfcb,  DMODEL*DMODEL);
  transpose_f2b<<<dim3(8,16,BATCH),256,0,stream>>>(q, x_rm, DMODEL, LTOK);
  qkv_gemm<<<dim3(128,8),256,0,stream>>>(x_rm, wqkvb, qh_sw, vtt);
  attn_k<<<512,512,0,stream>>>(qh_sw, vtt, ao);
  fc_gemm<<<dim3(128,8),256,0,stream>>>(ao, wfcb, fc_b, x_rm, y0);
  ln_k<<<2048,256,0,stream>>>(y0, ln_g, ln_b, out);
}